// Round 3
// baseline (173.276 us; speedup 1.0000x reference)
//
#include <hip/hip_runtime.h>
#include <math.h>

#define S_LEN 2048
#define BSZ 2
#define DM 512
#define NH 8
#define HD 64
#define RTOT (S_LEN*BSZ)             // 4096 rows, row r = s*BSZ + b
#define T_KEEP 32
#define ROW0 ((S_LEN - T_KEEP)*BSZ)  // 4032

typedef __attribute__((ext_vector_type(8))) _Float16 half8;
typedef __attribute__((ext_vector_type(4))) float floatx4;

__device__ __forceinline__ half8 pack8(float4 a, float4 b) {
    half8 h;
    h[0]=(_Float16)a.x; h[1]=(_Float16)a.y; h[2]=(_Float16)a.z; h[3]=(_Float16)a.w;
    h[4]=(_Float16)b.x; h[5]=(_Float16)b.y; h[6]=(_Float16)b.z; h[7]=(_Float16)b.w;
    return h;
}

// ---- Kernel 1 (MEGA): everything through spart/ssump/qsel + out bg-fill ------
// grid 256 = (xcd-swizzled rc 0..31) x (h 0..7); 1 block/CU, 64KB LDS.
// A: fp32 x -> fp16 in-register (no xf intermediate).
// B: fp32 Wq|Wk -> fp16 reg-staged into swizzled LDS (no wf intermediate).
//    LDS: chunk c (1KB) = rows 4c..4c+3, 256B/row, 16 slots of 16B;
//    position p of row j holds global slot s with p = s ^ (j&15).
//    Write side: lane puts slot s = (lane&15) ^ (j&15) at position lane&15.
//    Read side (verbatim R2, verified): slotp = (kc2*4+lk8) ^ lrow.
// Epilogue: sigmoid -> s_sig; qsel; PLAIN partial writes spart/ssump (no atomics,
// no zero-init needed -> convert kernel deleted).
__global__ __launch_bounds__(256, 1) void mega(
    const float* __restrict__ x,
    const float* __restrict__ Wq, const float* __restrict__ Wk,
    const float* __restrict__ bq, const float* __restrict__ bk,
    const float* __restrict__ beta, const float* __restrict__ bo,
    float* __restrict__ spart, float* __restrict__ ssump,
    float* __restrict__ qsel, float* __restrict__ out)
{
    __shared__ __align__(16) char smem[65536];   // 2 x 32KB W quarters; reused for sigma

    const int tid  = threadIdx.x;
    const int w    = tid >> 6;
    const int lane = tid & 63;
    const int lrow = lane & 15;
    const int lk8  = lane >> 4;
    const int bid  = blockIdx.x;
    // XCD-contiguous rc: xcd = bid&7 owns rc in [xcd*4, xcd*4+4) -> x rows L2-local
    const int rc   = (bid & 7)*4 + (bid >> 6);
    const int h    = (bid >> 3) & 7;
    const int r0   = rc * 128;

    // background out fill: rows < ROW0 are just bo; 2016 float4 per block
    {
        const float4* b4 = (const float4*)bo;
        float4* o4 = (float4*)out + (size_t)bid*2016;
        const int base = bid*2016;
        #pragma unroll
        for (int i = 0; i < 8; ++i) {
            int idx = i*256 + tid;
            if (idx < 2016) o4[idx] = b4[(base + idx) & 127];
        }
    }

    const int jsub = lk8;          // row within 4-row staging chunk
    const int l15  = lrow;

    // ---- stage W quarter 0 (fp32 load -> fp16 -> swizzled ds_write) ----
    #pragma unroll
    for (int i = 0; i < 8; ++i) {
        const int chunk = w*8 + i;
        const int j = chunk*4 + jsub;            // 0..63 = q (Wq), 64..127 = k (Wk)
        const int s = l15 ^ (j & 15);
        const float* src = (j < 64 ? Wq + (size_t)(h*HD + j)*DM
                                   : Wk + (size_t)(h*HD + j - 64)*DM) + s*8;
        float4 f0 = *(const float4*)src;
        float4 f1 = *(const float4*)(src + 4);
        *(half8*)(smem + chunk*1024 + jsub*256 + l15*16) = pack8(f0, f1);
    }

    // A pointers (fp32 x)
    const float* xA = x + (size_t)(r0 + w*16 + lrow)*DM + lk8*8;
    const float* xB = x + (size_t)(r0 + (w+4)*16 + lrow)*DM + lk8*8;

    half8 Aa[4], Ab[4];
    #pragma unroll
    for (int kc2 = 0; kc2 < 4; ++kc2) {
        Aa[kc2] = pack8(*(const float4*)(xA + kc2*32), *(const float4*)(xA + kc2*32 + 4));
        Ab[kc2] = pack8(*(const float4*)(xB + kc2*32), *(const float4*)(xB + kc2*32 + 4));
    }

    floatx4 acc[2][8];
    #pragma unroll
    for (int jt = 0; jt < 8; ++jt) { acc[0][jt] = (floatx4)0.f; acc[1][jt] = (floatx4)0.f; }

    __syncthreads();

    #pragma unroll
    for (int kq = 0; kq < 4; ++kq) {
        const char* buf = smem + (kq & 1)*32768;
        char* nb = smem + ((kq + 1) & 1)*32768;

        // T14 split: issue next-quarter loads BEFORE MFMAs, convert/write AFTER
        float4 AF[8], BF[8], WF0[8], WF1[8];
        if (kq < 3) {
            #pragma unroll
            for (int kc2 = 0; kc2 < 4; ++kc2) {
                AF[kc2*2]   = *(const float4*)(xA + (kq+1)*128 + kc2*32);
                AF[kc2*2+1] = *(const float4*)(xA + (kq+1)*128 + kc2*32 + 4);
                BF[kc2*2]   = *(const float4*)(xB + (kq+1)*128 + kc2*32);
                BF[kc2*2+1] = *(const float4*)(xB + (kq+1)*128 + kc2*32 + 4);
            }
            #pragma unroll
            for (int i = 0; i < 8; ++i) {
                const int chunk = w*8 + i;
                const int j = chunk*4 + jsub;
                const int s = l15 ^ (j & 15);
                const float* src = (j < 64 ? Wq + (size_t)(h*HD + j)*DM
                                           : Wk + (size_t)(h*HD + j - 64)*DM)
                                   + (kq+1)*128 + s*8;
                WF0[i] = *(const float4*)src;
                WF1[i] = *(const float4*)(src + 4);
            }
        }

        #pragma unroll
        for (int kc2 = 0; kc2 < 4; ++kc2) {
            #pragma unroll
            for (int jt = 0; jt < 8; ++jt) {
                const int j = jt*16 + lrow;
                const int slotp = (kc2*4 + lk8) ^ lrow;   // p = s ^ (j&15)
                half8 bf = *(const half8*)(buf + j*256 + slotp*16);
                acc[0][jt] = __builtin_amdgcn_mfma_f32_16x16x32_f16(Aa[kc2], bf, acc[0][jt], 0, 0, 0);
                acc[1][jt] = __builtin_amdgcn_mfma_f32_16x16x32_f16(Ab[kc2], bf, acc[1][jt], 0, 0, 0);
            }
        }

        if (kq < 3) {
            #pragma unroll
            for (int kc2 = 0; kc2 < 4; ++kc2) {
                Aa[kc2] = pack8(AF[kc2*2], AF[kc2*2+1]);
                Ab[kc2] = pack8(BF[kc2*2], BF[kc2*2+1]);
            }
            #pragma unroll
            for (int i = 0; i < 8; ++i) {
                const int chunk = w*8 + i;
                *(half8*)(nb + chunk*1024 + jsub*256 + l15*16) = pack8(WF0[i], WF1[i]);
            }
        }
        __syncthreads();
    }

    // ---- epilogue: sigma = sigmoid((q+bq).(k+bk) * isc); qsel for selected rows
    float* s_sig = (float*)smem;     // W no longer needed; reuse LDS
    float bqv[4], bkv[4];
    #pragma unroll
    for (int jt = 0; jt < 4; ++jt) {
        bqv[jt] = bq[h*HD + jt*16 + lrow];
        bkv[jt] = bk[h*HD + jt*16 + lrow];
    }
    const float isc = 1.0f / (8.0f * expf(beta[h]));

    #pragma unroll
    for (int t = 0; t < 2; ++t) {
        #pragma unroll
        for (int r = 0; r < 4; ++r) {
            float q[4]; float p = 0.f;
            #pragma unroll
            for (int jt = 0; jt < 4; ++jt) {
                float qv = acc[t][jt][r]   + bqv[jt];
                float kv = acc[t][jt+4][r] + bkv[jt];
                q[jt] = qv;
                p += qv * kv;
            }
            p += __shfl_xor(p, 1, 64);
            p += __shfl_xor(p, 2, 64);
            p += __shfl_xor(p, 4, 64);
            p += __shfl_xor(p, 8, 64);
            const int rowl = (w + t*4)*16 + lk8*4 + r;    // 0..127 within block
            if (lrow == 0)
                s_sig[rowl] = 1.0f / (1.0f + expf(-p * isc));
            if (rowl >= 126) {                            // s%64==63 rows (b=0,1)
                const int b = rowl & 1;
                float* qd = &qsel[((size_t)((b*NH + h)*T_KEEP) + rc)*64];
                #pragma unroll
                for (int jt = 0; jt < 4; ++jt) qd[jt*16 + lrow] = q[jt];
            }
        }
    }
    __syncthreads();

    // ---- spart partial (PLAIN writes, no atomics): thread = (b, 4-col group)
    {
        const int b  = tid & 1;
        const int cg = tid >> 1;
        const float* px = x + (size_t)(r0 + b)*DM + cg*4;
        float a0=0.f, a1=0.f, a2=0.f, a3=0.f;
        #pragma unroll 8
        for (int si = 0; si < 64; ++si) {
            const float sg = s_sig[si*2 + b];
            const float4 xv = *(const float4*)(px + (size_t)(si*2)*DM);
            a0 += sg*xv.x; a1 += sg*xv.y; a2 += sg*xv.z; a3 += sg*xv.w;
        }
        float4 st; st.x = a0; st.y = a1; st.z = a2; st.w = a3;
        *(float4*)&spart[((size_t)(rc*2 + b)*8 + h)*512 + cg*4] = st;
    }
    if (tid < 2) {
        float s = 0.f;
        for (int i = 0; i < 64; ++i) s += s_sig[i*2 + tid];
        ssump[(rc*2 + tid)*8 + h] = s;
    }
}

// ---- Kernel 2 (TAIL): spart-reduce -> kbar/vbar -> coef -> output ------------
// grid 64 = (b, col-chunk cc of 16). Each block redundantly computes the full
// per-batch head state (L2-hot Wk/Wv reads) -> no cross-block sync needed.
__global__ __launch_bounds__(256) void tail(
    const float* __restrict__ spart, const float* __restrict__ ssump,
    const float* __restrict__ qsel, const float* __restrict__ beta,
    const float* __restrict__ Wk, const float* __restrict__ bk,
    const float* __restrict__ Wv, const float* __restrict__ bv,
    const float* __restrict__ Wo, const float* __restrict__ bo,
    float* __restrict__ out)
{
    const int bidx = blockIdx.x;
    const int b  = bidx & 1;
    const int cc = bidx >> 1;      // 0..31
    const int tid = threadIdx.x;

    __shared__ float s_sb[NH*DM];      // 16 KB  sbar for all heads, this batch
    __shared__ float s_S[NH];
    __shared__ float s_kb[NH*HD];      //  2 KB
    __shared__ float s_vb[NH*HD];      //  2 KB
    __shared__ float s_cf[NH*T_KEEP];  //  1 KB
    __shared__ float s_gp[16][NH][2];

    // stage 1: sbar[h][c] = sum_rc spart[rc][b][h][c]; Ssum likewise
    #pragma unroll
    for (int g = 0; g < 4; ++g) {
        const int fidx = g*256 + tid;           // float4 index 0..1023
        const int hh = fidx >> 7;
        const int c4 = fidx & 127;
        float a0=0.f, a1=0.f, a2=0.f, a3=0.f;
        for (int rcc = 0; rcc < 32; ++rcc) {
            float4 v = *(const float4*)&spart[((size_t)(rcc*2 + b)*8 + hh)*512 + c4*4];
            a0 += v.x; a1 += v.y; a2 += v.z; a3 += v.w;
        }
        float4 st; st.x = a0; st.y = a1; st.z = a2; st.w = a3;
        *(float4*)&s_sb[fidx*4] = st;
    }
    if (tid < NH) {
        float s = 0.f;
        for (int rcc = 0; rcc < 32; ++rcc) s += ssump[(rcc*2 + b)*8 + tid];
        s_S[tid] = s;
    }
    __syncthreads();

    // stage 2: kbar/vbar = W*sbar + b*S (thread = (h, jq); 4 outputs each)
    {
        const int hh = tid >> 5;
        const int jq = tid & 31;
        const float* wk0 = &Wk[(size_t)(hh*HD + jq)*DM];
        const float* wk1 = &Wk[(size_t)(hh*HD + jq + 32)*DM];
        const float* wv0 = &Wv[(size_t)(hh*HD + jq)*DM];
        const float* wv1 = &Wv[(size_t)(hh*HD + jq + 32)*DM];
        const float* sb  = &s_sb[hh*DM];
        float ak0=0.f, ak1=0.f, av0=0.f, av1=0.f;
        for (int k = 0; k < DM; k += 4) {
            float4 s4 = *(const float4*)&sb[k];
            float4 a4 = *(const float4*)&wk0[k];
            float4 b4 = *(const float4*)&wk1[k];
            float4 c4 = *(const float4*)&wv0[k];
            float4 d4 = *(const float4*)&wv1[k];
            ak0 += a4.x*s4.x + a4.y*s4.y + a4.z*s4.z + a4.w*s4.w;
            ak1 += b4.x*s4.x + b4.y*s4.y + b4.z*s4.z + b4.w*s4.w;
            av0 += c4.x*s4.x + c4.y*s4.y + c4.z*s4.z + c4.w*s4.w;
            av1 += d4.x*s4.x + d4.y*s4.y + d4.z*s4.z + d4.w*s4.w;
        }
        const float S = s_S[hh];
        s_kb[hh*HD + jq]      = ak0 + bk[hh*HD + jq]*S;
        s_kb[hh*HD + jq + 32] = ak1 + bk[hh*HD + jq + 32]*S;
        s_vb[hh*HD + jq]      = av0 + bv[hh*HD + jq]*S;
        s_vb[hh*HD + jq + 32] = av1 + bv[hh*HD + jq + 32]*S;
    }
    __syncthreads();

    // stage 3: coef softmax with sink (thread = (h, wi); 32-lane groups)
    {
        const int hh = tid >> 5;
        const int wi = tid & 31;
        const float* qrow = &qsel[(((size_t)(b*NH + hh))*T_KEEP + wi)*64];
        const float* kb = &s_kb[hh*HD];
        float p = 0.f;
        #pragma unroll
        for (int j = 0; j < 64; j += 4) {
            float4 q4 = *(const float4*)&qrow[j];
            p += q4.x*kb[j] + q4.y*kb[j+1] + q4.z*kb[j+2] + q4.w*kb[j+3];
        }
        p *= 1.0f / (8.0f * expf(beta[hh]));
        float m = p;
        #pragma unroll
        for (int off = 16; off > 0; off >>= 1) m = fmaxf(m, __shfl_xor(m, off, 64));
        m = fmaxf(m, 0.f);                        // sink logit = 0
        float e = expf(p - m);
        float d = e;
        #pragma unroll
        for (int off = 16; off > 0; off >>= 1) d += __shfl_xor(d, off, 64);
        d += expf(-m);                            // sink term
        float c = e / d;
        if (wi == T_KEEP-1) c += 1.0f;            // iter-0 contribution
        s_cf[hh*T_KEEP + wi] = c;
    }
    __syncthreads();

    // stage 4: G partials for this col-chunk, then combine -> out
    {
        const int ci = tid & 15, hh = (tid >> 4) & 7, j2 = tid >> 7;
        const float* wr = &Wo[(size_t)(cc*16 + ci)*DM + hh*HD + j2*32];
        const float* vb = &s_vb[hh*HD + j2*32];
        float a = 0.f;
        #pragma unroll
        for (int j = 0; j < 32; j += 4) {
            float4 w4 = *(const float4*)&wr[j];
            a += w4.x*vb[j] + w4.y*vb[j+1] + w4.z*vb[j+2] + w4.w*vb[j+3];
        }
        s_gp[ci][hh][j2] = a;
    }
    __syncthreads();
    {
        const int ci = tid & 15;
        const float bov = bo[cc*16 + ci];
        #pragma unroll
        for (int hf = 0; hf < 2; ++hf) {
            const int wi = (tid >> 4) + hf*16;
            float v = bov;
            #pragma unroll
            for (int hh = 0; hh < NH; ++hh)
                v += s_cf[hh*T_KEEP + wi] * (s_gp[ci][hh][0] + s_gp[ci][hh][1]);
            out[(size_t)(ROW0 + wi*2 + b)*DM + cc*16 + ci] = v;
        }
    }
}

extern "C" void kernel_launch(void* const* d_in, const int* in_sizes, int n_in,
                              void* d_out, int out_size, void* d_ws, size_t ws_size,
                              hipStream_t stream) {
    const float* x    = (const float*)d_in[0];
    const float* Wq   = (const float*)d_in[1];
    const float* bq   = (const float*)d_in[2];
    const float* Wk   = (const float*)d_in[3];
    const float* bk   = (const float*)d_in[4];
    const float* Wv   = (const float*)d_in[5];
    const float* bv   = (const float*)d_in[6];
    const float* Wo   = (const float*)d_in[7];
    const float* bo   = (const float*)d_in[8];
    const float* beta = (const float*)d_in[9];

    char* ws = (char*)d_ws;
    float* spart = (float*)(ws + 0);              // 1 MB  [rc][b][h][512]
    float* ssump = (float*)(ws + 1048576);        // 2 KB  [rc*2+b][h]
    float* qsel  = (float*)(ws + 1052672);        // 128 KB [z][32][64]
    float* out   = (float*)d_out;

    mega<<<256, 256, 0, stream>>>(x, Wq, Wk, bq, bk, beta, bo,
                                  spart, ssump, qsel, out);
    tail<<<64, 256, 0, stream>>>(spart, ssump, qsel, beta,
                                 Wk, bk, Wv, bv, Wo, bo, out);
}

// Round 5
// 112.325 us; speedup vs baseline: 1.5426x; 1.5426x over previous
//
#include <hip/hip_runtime.h>
#include <math.h>

#define S_LEN 2048
#define BSZ 2
#define DM 512
#define NH 8
#define HD 64
#define RTOT (S_LEN*BSZ)             // 4096 rows, row r = s*BSZ + b
#define T_KEEP 32
#define ROW0 ((S_LEN - T_KEEP)*BSZ)  // 4032

typedef __attribute__((ext_vector_type(8))) _Float16 half8;
typedef __attribute__((ext_vector_type(4))) float floatx4;

__device__ __forceinline__ half8 pack8(float4 a, float4 b) {
    half8 h;
    h[0]=(_Float16)a.x; h[1]=(_Float16)a.y; h[2]=(_Float16)a.z; h[3]=(_Float16)a.w;
    h[4]=(_Float16)b.x; h[5]=(_Float16)b.y; h[6]=(_Float16)b.z; h[7]=(_Float16)b.w;
    return h;
}

// ---- Kernel 1 (MEGA): fused convert + q|k GEMM + sigmoid + partials ----------
// grid 256 = (xcd-swizzled rc 0..31) x (h 0..7); 1 block/CU, 64KB LDS.
// Register-budget discipline vs R3: only W is prefetched across the MFMA
// section (WF, 64 VGPR). A fragments are refilled IN PLACE per kc2 right
// after last use -> peak live ~190 VGPR (R3 held ~250+ -> suspected spills).
__global__ __launch_bounds__(256, 1) void mega(
    const float* __restrict__ x,
    const float* __restrict__ Wq, const float* __restrict__ Wk,
    const float* __restrict__ bq, const float* __restrict__ bk,
    const float* __restrict__ beta, const float* __restrict__ bo,
    float* __restrict__ spart, float* __restrict__ ssump,
    float* __restrict__ qsel, float* __restrict__ out)
{
    __shared__ __align__(16) char smem[65536];   // 2 x 32KB W quarters; reused for sigma

    const int tid  = threadIdx.x;
    const int w    = tid >> 6;
    const int lane = tid & 63;
    const int lrow = lane & 15;
    const int lk8  = lane >> 4;
    const int bid  = blockIdx.x;
    const int rc   = (bid & 7)*4 + (bid >> 6);
    const int h    = (bid >> 3) & 7;
    const int r0   = rc * 128;

    // background out fill: rows < ROW0 are just bo; 2016 float4 per block
    {
        const float4* b4 = (const float4*)bo;
        float4* o4 = (float4*)out + (size_t)bid*2016;
        const int base = bid*2016;
        #pragma unroll
        for (int i = 0; i < 8; ++i) {
            int idx = i*256 + tid;
            if (idx < 2016) o4[idx] = b4[(base + idx) & 127];
        }
    }

    const int jsub = lk8;          // row within 4-row staging chunk
    const int l15  = lrow;

    // ---- stage W quarter 0 (fp32 load -> fp16 -> ds_write; pos p = s ^ (j&15),
    //      realized by picking source slot s = l15 ^ (j&15), writing at l15) ----
    #pragma unroll
    for (int i = 0; i < 8; ++i) {
        const int chunk = w*8 + i;
        const int j = chunk*4 + jsub;            // 0..63 = q (Wq), 64..127 = k (Wk)
        const int s = l15 ^ (j & 15);
        const float* src = (j < 64 ? Wq + (size_t)(h*HD + j)*DM
                                   : Wk + (size_t)(h*HD + j - 64)*DM) + s*8;
        float4 f0 = *(const float4*)src;
        float4 f1 = *(const float4*)(src + 4);
        *(half8*)(smem + chunk*1024 + jsub*256 + l15*16) = pack8(f0, f1);
    }

    // A pointers (fp32 x)
    const float* xA = x + (size_t)(r0 + w*16 + lrow)*DM + lk8*8;
    const float* xB = x + (size_t)(r0 + (w+4)*16 + lrow)*DM + lk8*8;

    half8 Aa[4], Ab[4];
    #pragma unroll
    for (int kc2 = 0; kc2 < 4; ++kc2) {
        Aa[kc2] = pack8(*(const float4*)(xA + kc2*32), *(const float4*)(xA + kc2*32 + 4));
        Ab[kc2] = pack8(*(const float4*)(xB + kc2*32), *(const float4*)(xB + kc2*32 + 4));
    }

    floatx4 acc[2][8];
    #pragma unroll
    for (int jt = 0; jt < 8; ++jt) { acc[0][jt] = (floatx4)0.f; acc[1][jt] = (floatx4)0.f; }

    __syncthreads();

    #pragma unroll
    for (int kq = 0; kq < 4; ++kq) {
        const char* buf = smem + (kq & 1)*32768;
        char* nb = smem + ((kq + 1) & 1)*32768;

        // prefetch ONLY W for next quarter (issued before MFMAs, written after)
        float4 WF0[8], WF1[8];
        if (kq < 3) {
            #pragma unroll
            for (int i = 0; i < 8; ++i) {
                const int j = (w*8 + i)*4 + jsub;
                const int s = l15 ^ (j & 15);
                const float* src = (j < 64 ? Wq + (size_t)(h*HD + j)*DM
                                           : Wk + (size_t)(h*HD + j - 64)*DM)
                                   + (kq+1)*128 + s*8;
                WF0[i] = *(const float4*)src;
                WF1[i] = *(const float4*)(src + 4);
            }
        }

        #pragma unroll
        for (int kc2 = 0; kc2 < 4; ++kc2) {
            #pragma unroll
            for (int jt = 0; jt < 8; ++jt) {
                const int j = jt*16 + lrow;
                const int slotp = (kc2*4 + lk8) ^ lrow;   // p = s ^ (j&15)
                half8 bf = *(const half8*)(buf + j*256 + slotp*16);
                acc[0][jt] = __builtin_amdgcn_mfma_f32_16x16x32_f16(Aa[kc2], bf, acc[0][jt], 0, 0, 0);
                acc[1][jt] = __builtin_amdgcn_mfma_f32_16x16x32_f16(Ab[kc2], bf, acc[1][jt], 0, 0, 0);
            }
            if (kq < 3) {
                // refill A chunk kc2 for next quarter IN PLACE (last use was above)
                Aa[kc2] = pack8(*(const float4*)(xA + (kq+1)*128 + kc2*32),
                                *(const float4*)(xA + (kq+1)*128 + kc2*32 + 4));
                Ab[kc2] = pack8(*(const float4*)(xB + (kq+1)*128 + kc2*32),
                                *(const float4*)(xB + (kq+1)*128 + kc2*32 + 4));
            }
        }

        if (kq < 3) {
            #pragma unroll
            for (int i = 0; i < 8; ++i)
                *(half8*)(nb + (w*8 + i)*1024 + jsub*256 + l15*16) = pack8(WF0[i], WF1[i]);
        }
        __syncthreads();
    }

    // ---- epilogue: sigma = sigmoid((q+bq).(k+bk) * isc); qsel for selected rows
    float* s_sig = (float*)smem;     // W no longer needed; reuse LDS
    float bqv[4], bkv[4];
    #pragma unroll
    for (int jt = 0; jt < 4; ++jt) {
        bqv[jt] = bq[h*HD + jt*16 + lrow];
        bkv[jt] = bk[h*HD + jt*16 + lrow];
    }
    const float isc = 1.0f / (8.0f * expf(beta[h]));

    #pragma unroll
    for (int t = 0; t < 2; ++t) {
        #pragma unroll
        for (int r = 0; r < 4; ++r) {
            float q[4]; float p = 0.f;
            #pragma unroll
            for (int jt = 0; jt < 4; ++jt) {
                float qv = acc[t][jt][r]   + bqv[jt];
                float kv = acc[t][jt+4][r] + bkv[jt];
                q[jt] = qv;
                p += qv * kv;
            }
            p += __shfl_xor(p, 1, 64);
            p += __shfl_xor(p, 2, 64);
            p += __shfl_xor(p, 4, 64);
            p += __shfl_xor(p, 8, 64);
            const int rowl = (w + t*4)*16 + lk8*4 + r;    // 0..127 within block
            if (lrow == 0)
                s_sig[rowl] = 1.0f / (1.0f + expf(-p * isc));
            if (rowl >= 126) {                            // s%64==63 rows (b=0,1)
                const int b = rowl & 1;
                float* qd = &qsel[((size_t)((b*NH + h)*T_KEEP) + rc)*64];
                #pragma unroll
                for (int jt = 0; jt < 4; ++jt) qd[jt*16 + lrow] = q[jt];
            }
        }
    }
    __syncthreads();

    // ---- spart partial (PLAIN writes, no atomics): thread = (b, 4-col group)
    {
        const int b  = tid & 1;
        const int cg = tid >> 1;
        const float* px = x + (size_t)(r0 + b)*DM + cg*4;
        float a0=0.f, a1=0.f, a2=0.f, a3=0.f;
        #pragma unroll 8
        for (int si = 0; si < 64; ++si) {
            const float sg = s_sig[si*2 + b];
            const float4 xv = *(const float4*)(px + (size_t)(si*2)*DM);
            a0 += sg*xv.x; a1 += sg*xv.y; a2 += sg*xv.z; a3 += sg*xv.w;
        }
        float4 st; st.x = a0; st.y = a1; st.z = a2; st.w = a3;
        *(float4*)&spart[((size_t)(rc*2 + b)*8 + h)*512 + cg*4] = st;
    }
    if (tid < 2) {
        float s = 0.f;
        for (int i = 0; i < 64; ++i) s += s_sig[i*2 + tid];
        ssump[(rc*2 + tid)*8 + h] = s;
    }
}

// ---- Kernel 2: spart-reduce -> kbar/vbar -> coef (R2 kvbar_coef + reduce) ----
// grid 32 (z x {k,v}), block 256.
__global__ __launch_bounds__(256) void kvc(
    const float* __restrict__ spart, const float* __restrict__ ssump,
    const float* __restrict__ qsel, const float* __restrict__ beta,
    const float* __restrict__ Wk, const float* __restrict__ bk,
    const float* __restrict__ Wv, const float* __restrict__ bv,
    float* __restrict__ vbar, float* __restrict__ coef)
{
    const int z  = blockIdx.x >> 1;
    const int kv = blockIdx.x & 1;
    const int b  = z >> 3;
    const int h  = z & 7;
    const int tid = threadIdx.x;

    __shared__ float s_sb[DM];
    __shared__ float s_red[64][4];
    __shared__ float s_kb[64];
    __shared__ float s_part[T_KEEP][8];
    __shared__ float s_S;

    // stage 0: sbar = sum_rc spart (coalesced float2 cols); Ssum wave-reduce
    {
        const float2* sp = (const float2*)spart;
        float ax = 0.f, ay = 0.f;
        for (int rcc = 0; rcc < 32; ++rcc) {
            float2 v = sp[((size_t)(rcc*2 + b)*8 + h)*256 + tid];
            ax += v.x; ay += v.y;
        }
        s_sb[tid*2] = ax; s_sb[tid*2+1] = ay;
    }
    {
        float sv = 0.f;
        if (tid < 32) sv = ssump[(tid*2 + b)*8 + h];
        if (tid < 64) {
            sv += __shfl_xor(sv, 1, 64);
            sv += __shfl_xor(sv, 2, 64);
            sv += __shfl_xor(sv, 4, 64);
            sv += __shfl_xor(sv, 8, 64);
            sv += __shfl_xor(sv, 16, 64);
            if (tid == 0) s_S = sv;
        }
    }
    __syncthreads();
    const float S = s_S;

    const float* W    = kv ? Wv : Wk;
    const float* bvec = kv ? bv : bk;
    {
        const int j = tid >> 2, kp = tid & 3;
        const float* wr = &W[(size_t)(h*HD + j)*DM + kp*128];
        float a = 0.f;
        #pragma unroll
        for (int k = 0; k < 128; k += 4) {
            float4 w4 = *(const float4*)&wr[k];
            int k0 = kp*128 + k;
            a += w4.x*s_sb[k0] + w4.y*s_sb[k0+1] + w4.z*s_sb[k0+2] + w4.w*s_sb[k0+3];
        }
        s_red[j][kp] = a;
    }
    __syncthreads();
    if (tid < 64) {
        float val = s_red[tid][0]+s_red[tid][1]+s_red[tid][2]+s_red[tid][3]
                  + bvec[h*HD + tid]*S;
        if (kv) vbar[z*HD + tid] = val;
        else    s_kb[tid] = val;
    }
    if (kv) return;
    __syncthreads();
    {
        const int wi = tid >> 3, jg = tid & 7;
        const float* qrow = &qsel[((size_t)z*T_KEEP + wi)*64 + jg*8];
        float4 q1 = *(const float4*)qrow;
        float4 q2 = *(const float4*)(qrow + 4);
        const int j0 = jg*8;
        float p = q1.x*s_kb[j0]   + q1.y*s_kb[j0+1] + q1.z*s_kb[j0+2] + q1.w*s_kb[j0+3]
                + q2.x*s_kb[j0+4] + q2.y*s_kb[j0+5] + q2.z*s_kb[j0+6] + q2.w*s_kb[j0+7];
        s_part[wi][jg] = p;
    }
    __syncthreads();
    if (tid < T_KEEP) {
        float sc = 0.f;
        #pragma unroll
        for (int gg = 0; gg < 8; ++gg) sc += s_part[tid][gg];
        sc *= 1.0f / (8.0f * expf(beta[h]));
        float m = sc;
        #pragma unroll
        for (int off = 16; off > 0; off >>= 1) m = fmaxf(m, __shfl_xor(m, off, 64));
        m = fmaxf(m, 0.f);                        // sink logit = 0
        float e = expf(sc - m);
        float d = e;
        #pragma unroll
        for (int off = 16; off > 0; off >>= 1) d += __shfl_xor(d, off, 64);
        d += expf(-m);                            // sink term
        float c = e / d;
        if (tid == T_KEEP-1) c += 1.0f;           // iter-0 contribution
        coef[z*T_KEEP + tid] = c;
    }
}

// ---- Kernel 3: fused G + output combine (R2 gout verbatim) -------------------
// grid 64 (b x 32 col-chunks of 16). out[b,wi,c] = bo[c] + sum_h coef*G[h,c]
__global__ __launch_bounds__(256) void gout(
    const float* __restrict__ coef, const float* __restrict__ vbar,
    const float* __restrict__ Wo, const float* __restrict__ bo,
    float* __restrict__ out)
{
    const int b  = blockIdx.x & 1;
    const int cc = blockIdx.x >> 1;      // 0..31
    const int tid = threadIdx.x;

    __shared__ float s_cf[NH][T_KEEP];
    __shared__ float s_vb[NH*HD];
    __shared__ float s_gp[16][NH][2];

    s_vb[tid]       = vbar[b*512 + tid];
    s_vb[tid + 256] = vbar[b*512 + 256 + tid];
    s_cf[tid >> 5][tid & 31] = coef[((size_t)(b*NH) + (tid >> 5))*T_KEEP + (tid & 31)];
    __syncthreads();

    {
        const int ci = tid & 15, hh = (tid >> 4) & 7, j2 = tid >> 7;
        const float* wr = &Wo[(size_t)(cc*16 + ci)*DM + hh*HD + j2*32];
        const float* vb = &s_vb[hh*HD + j2*32];
        float a = 0.f;
        #pragma unroll
        for (int j = 0; j < 32; j += 4) {
            float4 w4 = *(const float4*)&wr[j];
            a += w4.x*vb[j] + w4.y*vb[j+1] + w4.z*vb[j+2] + w4.w*vb[j+3];
        }
        s_gp[ci][hh][j2] = a;
    }
    __syncthreads();
    {
        const int ci = tid & 15;
        const float bov = bo[cc*16 + ci];
        #pragma unroll
        for (int hf = 0; hf < 2; ++hf) {
            const int wi = (tid >> 4) + hf*16;
            float v = bov;
            #pragma unroll
            for (int hh = 0; hh < NH; ++hh)
                v += s_cf[hh][wi] * (s_gp[ci][hh][0] + s_gp[ci][hh][1]);
            out[(size_t)(ROW0 + wi*2 + b)*DM + cc*16 + ci] = v;
        }
    }
}

extern "C" void kernel_launch(void* const* d_in, const int* in_sizes, int n_in,
                              void* d_out, int out_size, void* d_ws, size_t ws_size,
                              hipStream_t stream) {
    const float* x    = (const float*)d_in[0];
    const float* Wq   = (const float*)d_in[1];
    const float* bq   = (const float*)d_in[2];
    const float* Wk   = (const float*)d_in[3];
    const float* bk   = (const float*)d_in[4];
    const float* Wv   = (const float*)d_in[5];
    const float* bv   = (const float*)d_in[6];
    const float* Wo   = (const float*)d_in[7];
    const float* bo   = (const float*)d_in[8];
    const float* beta = (const float*)d_in[9];

    char* ws = (char*)d_ws;
    float* spart = (float*)(ws + 0);              // 1 MB   [rc][b][h][512]
    float* ssump = (float*)(ws + 1048576);        // 2 KB   [rc*2+b][h]
    float* qsel  = (float*)(ws + 1052672);        // 128 KB [z][32][64]
    float* vbar  = (float*)(ws + 1183744);        // 4 KB   [z][64]
    float* coef  = (float*)(ws + 1187840);        // 2 KB   [z][32]
    float* out   = (float*)d_out;

    mega<<<256, 256, 0, stream>>>(x, Wq, Wk, bq, bk, beta, bo,
                                  spart, ssump, qsel, out);
    kvc<<<32, 256, 0, stream>>>(spart, ssump, qsel, beta,
                                Wk, bk, Wv, bv, vbar, coef);
    gout<<<64, 256, 0, stream>>>(coef, vbar, Wo, bo, out);
}

// Round 6
// 111.783 us; speedup vs baseline: 1.5501x; 1.0049x over previous
//
#include <hip/hip_runtime.h>
#include <math.h>

#define S_LEN 2048
#define BSZ 2
#define DM 512
#define NH 8
#define HD 64
#define RTOT (S_LEN*BSZ)             // 4096 rows, row r = s*BSZ + b
#define T_KEEP 32
#define ROW0 ((S_LEN - T_KEEP)*BSZ)  // 4032

typedef __attribute__((ext_vector_type(8))) _Float16 half8;
typedef __attribute__((ext_vector_type(4))) float floatx4;

__device__ __forceinline__ half8 pack8(float4 a, float4 b) {
    half8 h;
    h[0]=(_Float16)a.x; h[1]=(_Float16)a.y; h[2]=(_Float16)a.z; h[3]=(_Float16)a.w;
    h[4]=(_Float16)b.x; h[5]=(_Float16)b.y; h[6]=(_Float16)b.z; h[7]=(_Float16)b.w;
    return h;
}

// ---- Kernel 1 (MEGA): fused convert + q|k GEMM + sigmoid + partials ----------
// grid 256 = (xcd-swizzled rc 0..31) x (h 0..7); 1 block/CU, 64KB LDS.
__global__ __launch_bounds__(256, 1) void mega(
    const float* __restrict__ x,
    const float* __restrict__ Wq, const float* __restrict__ Wk,
    const float* __restrict__ bq, const float* __restrict__ bk,
    const float* __restrict__ beta, const float* __restrict__ bo,
    float* __restrict__ spart, float* __restrict__ ssump,
    float* __restrict__ qsel, float* __restrict__ out)
{
    __shared__ __align__(16) char smem[65536];   // 2 x 32KB W quarters; reused for sigma

    const int tid  = threadIdx.x;
    const int w    = tid >> 6;
    const int lane = tid & 63;
    const int lrow = lane & 15;
    const int lk8  = lane >> 4;
    const int bid  = blockIdx.x;
    const int rc   = (bid & 7)*4 + (bid >> 6);
    const int h    = (bid >> 3) & 7;
    const int r0   = rc * 128;

    // background out fill: rows < ROW0 are just bo; 2016 float4 per block
    {
        const float4* b4 = (const float4*)bo;
        float4* o4 = (float4*)out + (size_t)bid*2016;
        const int base = bid*2016;
        #pragma unroll
        for (int i = 0; i < 8; ++i) {
            int idx = i*256 + tid;
            if (idx < 2016) o4[idx] = b4[(base + idx) & 127];
        }
    }

    const int jsub = lk8;          // row within 4-row staging chunk
    const int l15  = lrow;

    // ---- stage W quarter 0 (fp32 load -> fp16 -> ds_write; pos p = s ^ (j&15),
    //      realized by picking source slot s = l15 ^ (j&15), writing at l15) ----
    #pragma unroll
    for (int i = 0; i < 8; ++i) {
        const int chunk = w*8 + i;
        const int j = chunk*4 + jsub;            // 0..63 = q (Wq), 64..127 = k (Wk)
        const int s = l15 ^ (j & 15);
        const float* src = (j < 64 ? Wq + (size_t)(h*HD + j)*DM
                                   : Wk + (size_t)(h*HD + j - 64)*DM) + s*8;
        float4 f0 = *(const float4*)src;
        float4 f1 = *(const float4*)(src + 4);
        *(half8*)(smem + chunk*1024 + jsub*256 + l15*16) = pack8(f0, f1);
    }

    // A pointers (fp32 x)
    const float* xA = x + (size_t)(r0 + w*16 + lrow)*DM + lk8*8;
    const float* xB = x + (size_t)(r0 + (w+4)*16 + lrow)*DM + lk8*8;

    half8 Aa[4], Ab[4];
    #pragma unroll
    for (int kc2 = 0; kc2 < 4; ++kc2) {
        Aa[kc2] = pack8(*(const float4*)(xA + kc2*32), *(const float4*)(xA + kc2*32 + 4));
        Ab[kc2] = pack8(*(const float4*)(xB + kc2*32), *(const float4*)(xB + kc2*32 + 4));
    }

    floatx4 acc[2][8];
    #pragma unroll
    for (int jt = 0; jt < 8; ++jt) { acc[0][jt] = (floatx4)0.f; acc[1][jt] = (floatx4)0.f; }

    __syncthreads();

    #pragma unroll
    for (int kq = 0; kq < 4; ++kq) {
        const char* buf = smem + (kq & 1)*32768;
        char* nb = smem + ((kq + 1) & 1)*32768;

        // prefetch ONLY W for next quarter (issued before MFMAs, written after)
        float4 WF0[8], WF1[8];
        if (kq < 3) {
            #pragma unroll
            for (int i = 0; i < 8; ++i) {
                const int j = (w*8 + i)*4 + jsub;
                const int s = l15 ^ (j & 15);
                const float* src = (j < 64 ? Wq + (size_t)(h*HD + j)*DM
                                           : Wk + (size_t)(h*HD + j - 64)*DM)
                                   + (kq+1)*128 + s*8;
                WF0[i] = *(const float4*)src;
                WF1[i] = *(const float4*)(src + 4);
            }
        }

        #pragma unroll
        for (int kc2 = 0; kc2 < 4; ++kc2) {
            #pragma unroll
            for (int jt = 0; jt < 8; ++jt) {
                const int j = jt*16 + lrow;
                const int slotp = (kc2*4 + lk8) ^ lrow;   // p = s ^ (j&15)
                half8 bf = *(const half8*)(buf + j*256 + slotp*16);
                acc[0][jt] = __builtin_amdgcn_mfma_f32_16x16x32_f16(Aa[kc2], bf, acc[0][jt], 0, 0, 0);
                acc[1][jt] = __builtin_amdgcn_mfma_f32_16x16x32_f16(Ab[kc2], bf, acc[1][jt], 0, 0, 0);
            }
            if (kq < 3) {
                // refill A chunk kc2 for next quarter IN PLACE (last use was above)
                Aa[kc2] = pack8(*(const float4*)(xA + (kq+1)*128 + kc2*32),
                                *(const float4*)(xA + (kq+1)*128 + kc2*32 + 4));
                Ab[kc2] = pack8(*(const float4*)(xB + (kq+1)*128 + kc2*32),
                                *(const float4*)(xB + (kq+1)*128 + kc2*32 + 4));
            }
        }

        if (kq < 3) {
            #pragma unroll
            for (int i = 0; i < 8; ++i)
                *(half8*)(nb + (w*8 + i)*1024 + jsub*256 + l15*16) = pack8(WF0[i], WF1[i]);
        }
        __syncthreads();
    }

    // ---- epilogue: sigma = sigmoid((q+bq).(k+bk) * isc); qsel for selected rows
    float* s_sig = (float*)smem;     // W no longer needed; reuse LDS
    float bqv[4], bkv[4];
    #pragma unroll
    for (int jt = 0; jt < 4; ++jt) {
        bqv[jt] = bq[h*HD + jt*16 + lrow];
        bkv[jt] = bk[h*HD + jt*16 + lrow];
    }
    const float isc = 1.0f / (8.0f * expf(beta[h]));

    #pragma unroll
    for (int t = 0; t < 2; ++t) {
        #pragma unroll
        for (int r = 0; r < 4; ++r) {
            float q[4]; float p = 0.f;
            #pragma unroll
            for (int jt = 0; jt < 4; ++jt) {
                float qv = acc[t][jt][r]   + bqv[jt];
                float kv = acc[t][jt+4][r] + bkv[jt];
                q[jt] = qv;
                p += qv * kv;
            }
            p += __shfl_xor(p, 1, 64);
            p += __shfl_xor(p, 2, 64);
            p += __shfl_xor(p, 4, 64);
            p += __shfl_xor(p, 8, 64);
            const int rowl = (w + t*4)*16 + lk8*4 + r;    // 0..127 within block
            if (lrow == 0)
                s_sig[rowl] = 1.0f / (1.0f + expf(-p * isc));
            if (rowl >= 126) {                            // s%64==63 rows (b=0,1)
                const int b = rowl & 1;
                float* qd = &qsel[((size_t)((b*NH + h)*T_KEEP) + rc)*64];
                #pragma unroll
                for (int jt = 0; jt < 4; ++jt) qd[jt*16 + lrow] = q[jt];
            }
        }
    }
    __syncthreads();

    // ---- spart partial (PLAIN writes, no atomics): thread = (b, 4-col group)
    {
        const int b  = tid & 1;
        const int cg = tid >> 1;
        const float* px = x + (size_t)(r0 + b)*DM + cg*4;
        float a0=0.f, a1=0.f, a2=0.f, a3=0.f;
        #pragma unroll 16
        for (int si = 0; si < 64; ++si) {
            const float sg = s_sig[si*2 + b];
            const float4 xv = *(const float4*)(px + (size_t)(si*2)*DM);
            a0 += sg*xv.x; a1 += sg*xv.y; a2 += sg*xv.z; a3 += sg*xv.w;
        }
        float4 st; st.x = a0; st.y = a1; st.z = a2; st.w = a3;
        *(float4*)&spart[((size_t)(rc*2 + b)*8 + h)*512 + cg*4] = st;
    }
    if (tid < 2) {
        float s = 0.f;
        for (int i = 0; i < 64; ++i) s += s_sig[i*2 + tid];
        ssump[(rc*2 + tid)*8 + h] = s;
    }
}

// ---- Kernel 2: spart-reduce -> kbar/vbar -> coef (grid 32 = z x {k,v}) ------
__global__ __launch_bounds__(256) void kvc(
    const float* __restrict__ spart, const float* __restrict__ ssump,
    const float* __restrict__ qsel, const float* __restrict__ beta,
    const float* __restrict__ Wk, const float* __restrict__ bk,
    const float* __restrict__ Wv, const float* __restrict__ bv,
    float* __restrict__ vbar, float* __restrict__ coef)
{
    const int z  = blockIdx.x >> 1;
    const int kv = blockIdx.x & 1;
    const int b  = z >> 3;
    const int h  = z & 7;
    const int tid = threadIdx.x;

    __shared__ float s_sb[DM];
    __shared__ float s_red[64][4];
    __shared__ float s_kb[64];
    __shared__ float s_part[T_KEEP][8];
    __shared__ float s_S;

    // stage 0: sbar = sum_rc spart. UNROLLED so all 32 loads are in flight
    // (rolled version serialized 32 x ~400cy L2 round-trips -- the R3/R5
    // latency pathology).
    {
        const float2* sp = (const float2*)spart;
        float ax = 0.f, ay = 0.f;
        #pragma unroll
        for (int rcc = 0; rcc < 32; ++rcc) {
            float2 v = sp[((size_t)(rcc*2 + b)*8 + h)*256 + tid];
            ax += v.x; ay += v.y;
        }
        s_sb[tid*2] = ax; s_sb[tid*2+1] = ay;
    }
    {
        float sv = 0.f;
        if (tid < 32) sv = ssump[(tid*2 + b)*8 + h];
        if (tid < 64) {
            sv += __shfl_xor(sv, 1, 64);
            sv += __shfl_xor(sv, 2, 64);
            sv += __shfl_xor(sv, 4, 64);
            sv += __shfl_xor(sv, 8, 64);
            sv += __shfl_xor(sv, 16, 64);
            if (tid == 0) s_S = sv;
        }
    }
    __syncthreads();
    const float S = s_S;

    const float* W    = kv ? Wv : Wk;
    const float* bvec = kv ? bv : bk;
    {
        const int j = tid >> 2, kp = tid & 3;
        const float* wr = &W[(size_t)(h*HD + j)*DM + kp*128];
        float a = 0.f;
        #pragma unroll
        for (int k = 0; k < 128; k += 4) {
            float4 w4 = *(const float4*)&wr[k];
            int k0 = kp*128 + k;
            a += w4.x*s_sb[k0] + w4.y*s_sb[k0+1] + w4.z*s_sb[k0+2] + w4.w*s_sb[k0+3];
        }
        s_red[j][kp] = a;
    }
    __syncthreads();
    if (tid < 64) {
        float val = s_red[tid][0]+s_red[tid][1]+s_red[tid][2]+s_red[tid][3]
                  + bvec[h*HD + tid]*S;
        if (kv) vbar[z*HD + tid] = val;
        else    s_kb[tid] = val;
    }
    if (kv) return;
    __syncthreads();
    {
        const int wi = tid >> 3, jg = tid & 7;
        const float* qrow = &qsel[((size_t)z*T_KEEP + wi)*64 + jg*8];
        float4 q1 = *(const float4*)qrow;
        float4 q2 = *(const float4*)(qrow + 4);
        const int j0 = jg*8;
        float p = q1.x*s_kb[j0]   + q1.y*s_kb[j0+1] + q1.z*s_kb[j0+2] + q1.w*s_kb[j0+3]
                + q2.x*s_kb[j0+4] + q2.y*s_kb[j0+5] + q2.z*s_kb[j0+6] + q2.w*s_kb[j0+7];
        s_part[wi][jg] = p;
    }
    __syncthreads();
    if (tid < T_KEEP) {
        float sc = 0.f;
        #pragma unroll
        for (int gg = 0; gg < 8; ++gg) sc += s_part[tid][gg];
        sc *= 1.0f / (8.0f * expf(beta[h]));
        float m = sc;
        #pragma unroll
        for (int off = 16; off > 0; off >>= 1) m = fmaxf(m, __shfl_xor(m, off, 64));
        m = fmaxf(m, 0.f);                        // sink logit = 0
        float e = expf(sc - m);
        float d = e;
        #pragma unroll
        for (int off = 16; off > 0; off >>= 1) d += __shfl_xor(d, off, 64);
        d += expf(-m);                            // sink term
        float c = e / d;
        if (tid == T_KEEP-1) c += 1.0f;           // iter-0 contribution
        coef[z*T_KEEP + tid] = c;
    }
}

// ---- Kernel 3: fused G + output combine --------------------------------------
// grid 64 (b x 32 col-chunks of 16). out[b,wi,c] = bo[c] + sum_h coef*G[h,c]
__global__ __launch_bounds__(256) void gout(
    const float* __restrict__ coef, const float* __restrict__ vbar,
    const float* __restrict__ Wo, const float* __restrict__ bo,
    float* __restrict__ out)
{
    const int b  = blockIdx.x & 1;
    const int cc = blockIdx.x >> 1;      // 0..31
    const int tid = threadIdx.x;

    __shared__ float s_cf[NH][T_KEEP];
    __shared__ float s_vb[NH*HD];
    __shared__ float s_gp[16][NH][2];

    s_vb[tid]       = vbar[b*512 + tid];
    s_vb[tid + 256] = vbar[b*512 + 256 + tid];
    s_cf[tid >> 5][tid & 31] = coef[((size_t)(b*NH) + (tid >> 5))*T_KEEP + (tid & 31)];
    __syncthreads();

    {
        const int ci = tid & 15, hh = (tid >> 4) & 7, j2 = tid >> 7;
        const float* wr = &Wo[(size_t)(cc*16 + ci)*DM + hh*HD + j2*32];
        const float* vb = &s_vb[hh*HD + j2*32];
        float a = 0.f;
        #pragma unroll
        for (int j = 0; j < 32; j += 4) {
            float4 w4 = *(const float4*)&wr[j];
            a += w4.x*vb[j] + w4.y*vb[j+1] + w4.z*vb[j+2] + w4.w*vb[j+3];
        }
        s_gp[ci][hh][j2] = a;
    }
    __syncthreads();
    {
        const int ci = tid & 15;
        const float bov = bo[cc*16 + ci];
        #pragma unroll
        for (int hf = 0; hf < 2; ++hf) {
            const int wi = (tid >> 4) + hf*16;
            float v = bov;
            #pragma unroll
            for (int hh = 0; hh < NH; ++hh)
                v += s_cf[hh][wi] * (s_gp[ci][hh][0] + s_gp[ci][hh][1]);
            out[(size_t)(ROW0 + wi*2 + b)*DM + cc*16 + ci] = v;
        }
    }
}

extern "C" void kernel_launch(void* const* d_in, const int* in_sizes, int n_in,
                              void* d_out, int out_size, void* d_ws, size_t ws_size,
                              hipStream_t stream) {
    const float* x    = (const float*)d_in[0];
    const float* Wq   = (const float*)d_in[1];
    const float* bq   = (const float*)d_in[2];
    const float* Wk   = (const float*)d_in[3];
    const float* bk   = (const float*)d_in[4];
    const float* Wv   = (const float*)d_in[5];
    const float* bv   = (const float*)d_in[6];
    const float* Wo   = (const float*)d_in[7];
    const float* bo   = (const float*)d_in[8];
    const float* beta = (const float*)d_in[9];

    char* ws = (char*)d_ws;
    float* spart = (float*)(ws + 0);              // 1 MB   [rc][b][h][512]
    float* ssump = (float*)(ws + 1048576);        // 2 KB   [rc*2+b][h]
    float* qsel  = (float*)(ws + 1052672);        // 128 KB [z][32][64]
    float* vbar  = (float*)(ws + 1183744);        // 4 KB   [z][64]
    float* coef  = (float*)(ws + 1187840);        // 2 KB   [z][32]
    float* out   = (float*)d_out;

    mega<<<256, 256, 0, stream>>>(x, Wq, Wk, bq, bk, beta, bo,
                                  spart, ssump, qsel, out);
    kvc<<<32, 256, 0, stream>>>(spart, ssump, qsel, beta,
                                Wk, bk, Wv, bv, vbar, coef);
    gout<<<64, 256, 0, stream>>>(coef, vbar, Wo, bo, out);
}